// Round 4
// baseline (492.088 us; speedup 1.0000x reference)
//
#include <hip/hip_runtime.h>
#include <math.h>

typedef __attribute__((ext_vector_type(8))) short bf16x8;
typedef __attribute__((ext_vector_type(4))) float f32x4;

__device__ __forceinline__ float bf2f(unsigned short s) {
    return __uint_as_float(((unsigned)s) << 16);
}
__device__ __forceinline__ unsigned short f2bf(float f) {
    unsigned u = __float_as_uint(f);
    unsigned r = (u + 0x7fffu + ((u >> 16) & 1u)) >> 16;   // RNE
    return (unsigned short)r;
}

// ---------------- K1: per-edge rank + deg histogram (single atomic) ----------------
__global__ __launch_bounds__(256) void edge_rank_kernel(
    const int* __restrict__ dst, int* __restrict__ cursor, int* __restrict__ rank, int E)
{
    int e = blockIdx.x * 256 + threadIdx.x;
    if (e < E) {
        rank[e] = atomicAdd(&cursor[dst[e]], 1);
    }
}

// ---------------- K2a: per-block reduce of deg ----------------
__global__ __launch_bounds__(256) void block_reduce_kernel(
    const int* __restrict__ deg, int* __restrict__ bsum, int N)
{
    __shared__ int sd[256];
    int t = threadIdx.x;
    int i = blockIdx.x * 256 + t;
    sd[t] = (i < N) ? deg[i] : 0;
    __syncthreads();
    for (int s = 128; s > 0; s >>= 1) {
        if (t < s) sd[t] += sd[t + s];
        __syncthreads();
    }
    if (t == 0) bsum[blockIdx.x] = sd[0];
}

// ---------------- K2b: scan block sums (single block) ----------------
__global__ __launch_bounds__(1024) void scan_bsums_kernel(
    const int* __restrict__ bsum, int* __restrict__ bscan, int nb)
{
    __shared__ int sd[1024];
    int t = threadIdx.x;
    int own = (t < nb) ? bsum[t] : 0;
    sd[t] = own;
    __syncthreads();
    for (int off = 1; off < 1024; off <<= 1) {
        int v = (t >= off) ? sd[t - off] : 0;
        __syncthreads();
        sd[t] += v;
        __syncthreads();
    }
    if (t < nb) bscan[t] = sd[t] - own;   // exclusive prefix
}

// ---------------- K2c: per-block exclusive scan -> offsets ----------------
__global__ __launch_bounds__(256) void block_scan_kernel(
    const int* __restrict__ deg, const int* __restrict__ bscan,
    int* __restrict__ offs, int N)
{
    __shared__ int sd[256];
    int t = threadIdx.x;
    int i = blockIdx.x * 256 + t;
    int myv = (i < N) ? deg[i] : 0;
    sd[t] = myv;
    __syncthreads();
    for (int off = 1; off < 256; off <<= 1) {
        int v = (t >= off) ? sd[t - off] : 0;
        __syncthreads();
        sd[t] += v;
        __syncthreads();
    }
    if (i < N) {
        offs[i] = sd[t] - myv + bscan[blockIdx.x];
    }
}

// ---------------- K3: scatter edges into CSR (no atomics, packed 8B) ----------------
__global__ __launch_bounds__(256) void csr_scatter_kernel(
    const int* __restrict__ src, const int* __restrict__ dst, const float* __restrict__ eig,
    const int* __restrict__ rank, const int* __restrict__ offs,
    int2* __restrict__ csr, int E)
{
    int e = blockIdx.x * 256 + threadIdx.x;
    if (e < E) {
        int dn = dst[e];
        int p = offs[dn] + rank[e];
        csr[p] = make_int2(src[e], __float_as_int(eig[e]));
    }
}

// ---------------- K4: u = h @ A^T ; v = h @ B^T + b1 (bf16 outputs) ----------------
__global__ __launch_bounds__(256) void uv_kernel(
    const float* __restrict__ h, const float* __restrict__ W1, const float* __restrict__ b1,
    unsigned short* __restrict__ u, unsigned short* __restrict__ v, int N)
{
    __shared__ float wT[64 * 128];   // wT[j*128 + c]
    __shared__ float hs[64 * 68];    // hs[n*68 + j], padded
    int t = threadIdx.x;
    for (int idx = t; idx < 64 * 128; idx += 256) {
        int j = idx >> 7, c = idx & 127;
        int d = c & 63;
        int col = (c < 64) ? j : (64 + j);
        wT[idx] = W1[d * 128 + col];
    }
    int n0 = blockIdx.x * 64;
    for (int r = 0; r < 16; ++r) {
        int idx = r * 256 + t;
        int nl = idx >> 6, j = idx & 63;
        int n = n0 + nl;
        hs[nl * 68 + j] = (n < N) ? h[(size_t)n * 64 + j] : 0.f;
    }
    __syncthreads();

    int nb = (t & 15) * 4;
    int cb = (t >> 4) * 8;
    float acc[4][8];
#pragma unroll
    for (int i = 0; i < 4; ++i)
#pragma unroll
        for (int k = 0; k < 8; ++k) acc[i][k] = 0.f;

    for (int j = 0; j < 64; ++j) {
        float wv[8];
#pragma unroll
        for (int k = 0; k < 8; ++k) wv[k] = wT[j * 128 + cb + k];
#pragma unroll
        for (int i = 0; i < 4; ++i) {
            float hv = hs[(nb + i) * 68 + j];
#pragma unroll
            for (int k = 0; k < 8; ++k) acc[i][k] = fmaf(hv, wv[k], acc[i][k]);
        }
    }

    bool isV = (cb >= 64);
    int dbase = cb & 63;
#pragma unroll
    for (int i = 0; i < 4; ++i) {
        int n = n0 + nb + i;
        if (n < N) {
            union { unsigned short s[8]; uint4 v4; } pk;
            if (!isV) {
#pragma unroll
                for (int k = 0; k < 8; ++k) pk.s[k] = f2bf(acc[i][k]);
                *(uint4*)(u + (size_t)n * 64 + dbase) = pk.v4;
            } else {
#pragma unroll
                for (int k = 0; k < 8; ++k) pk.s[k] = f2bf(acc[i][k] + b1[dbase + k]);
                *(uint4*)(v + (size_t)n * 64 + dbase) = pk.v4;
            }
        }
    }
}

// ---------------- K4b: W2 -> bf16 (same row-major [64][256] layout) ----------------
__global__ __launch_bounds__(256) void w2b_kernel(
    const float* __restrict__ W2, unsigned short* __restrict__ w2b)
{
    int idx = blockIdx.x * 256 + threadIdx.x;
    if (idx < 64 * 256) w2b[idx] = f2bf(W2[idx]);
}

// ---------------- K5: aggregation, one wave per node -> hc[N][256] bf16 ----------------
__global__ __launch_bounds__(256) void agg_kernel(
    const unsigned short* __restrict__ u, const unsigned short* __restrict__ v,
    const float* __restrict__ h,
    const int* __restrict__ offs, const int* __restrict__ degi,
    const int2* __restrict__ csr,
    unsigned short* __restrict__ hc, int N)
{
    int gw = (blockIdx.x * 256 + threadIdx.x) >> 6;
    int lane = threadIdx.x & 63;
    int n = __builtin_amdgcn_readfirstlane(gw);
    if (n >= N) return;
    int beg = offs[n];
    int dn = degi[n];

    float accs = 0.f, accd = 0.f, accm = -3.402823466e38f;
    float pa = 0.f, ps = 0.f;   // per-lane partials for absum / sege
    for (int i0 = 0; i0 < dn; i0 += 64) {
        int cnt = min(dn - i0, 64);
        int idxv = 0; float wvv = 0.f;
        if (lane < cnt) {
            int2 rec = csr[beg + i0 + lane];
            idxv = rec.x;
            wvv = __int_as_float(rec.y);
        }
        pa += fabsf(wvv);
        ps += wvv;
        int j = 0;
        for (; j + 4 <= cnt; j += 4) {
            int s0 = __shfl(idxv, j), s1 = __shfl(idxv, j + 1);
            int s2 = __shfl(idxv, j + 2), s3 = __shfl(idxv, j + 3);
            float w0 = __shfl(wvv, j), w1 = __shfl(wvv, j + 1);
            float w2_ = __shfl(wvv, j + 2), w3 = __shfl(wvv, j + 3);
            float u0 = bf2f(u[(size_t)s0 * 64 + lane]);
            float u1 = bf2f(u[(size_t)s1 * 64 + lane]);
            float u2 = bf2f(u[(size_t)s2 * 64 + lane]);
            float u3 = bf2f(u[(size_t)s3 * 64 + lane]);
            accs += (u0 + u1) + (u2 + u3);
            accm = fmaxf(accm, fmaxf(fmaxf(u0, u1), fmaxf(u2, u3)));
            accd = fmaf(w0, u0, fmaf(w1, u1, fmaf(w2_, u2, fmaf(w3, u3, accd))));
        }
        for (; j < cnt; ++j) {
            int s0 = __shfl(idxv, j);
            float w0 = __shfl(wvv, j);
            float u0 = bf2f(u[(size_t)s0 * 64 + lane]);
            accs += u0;
            accm = fmaxf(accm, u0);
            accd = fmaf(w0, u0, accd);
        }
    }
#pragma unroll
    for (int w = 1; w < 64; w <<= 1) {
        pa += __shfl_xor(pa, w);
        ps += __shfl_xor(ps, w);
    }
    float inv_ab = 1.f / (pa + 1e-8f);
    float segw = ps * inv_ab;

    float vl = bf2f(v[(size_t)n * 64 + lane]);
    float hl = h[(size_t)n * 64 + lane];
    float fdeg = (float)dn;
    float mean = (accs + fdeg * vl) / fmaxf(fdeg, 1.f);
    float amax = (dn > 0) ? (accm + vl) : 0.f;
    float adir = fabsf(fmaf(accd, inv_ab, segw * (vl - hl)));
    size_t base = (size_t)n * 256;
    hc[base + lane]       = f2bf(hl);
    hc[base + 64 + lane]  = f2bf(mean);
    hc[base + 128 + lane] = f2bf(amax);
    hc[base + 192 + lane] = f2bf(adir);
}

// ---------------- K6: posttrans via MFMA: h2 = hc @ W2^T, + BN partials ----------------
// block = 64 nodes, 4 waves; wave w: 16-row stripe (m0 = w*16), 4 col-tiles of 16.
// A fragment loaded straight from global hc (bf16, fragment-native layout),
// B fragment straight from w2b (row-major [d][k] == B operand layout). No LDS.
__global__ __launch_bounds__(256) void post_mfma_kernel(
    const unsigned short* __restrict__ hc, const unsigned short* __restrict__ w2b,
    const float* __restrict__ b2, const float* __restrict__ snorm,
    float* __restrict__ h2, float* __restrict__ bn_buf, int N)
{
    int tid = threadIdx.x;
    int lane = tid & 63;
    int wv = tid >> 6;
    int l15 = lane & 15;
    int quad = lane >> 4;
    int n0 = blockIdx.x * 64;
    int m0 = n0 + wv * 16;

    const unsigned short* aptr = hc + (size_t)(m0 + l15) * 256 + quad * 8;
    const unsigned short* bptr = w2b + (size_t)l15 * 256 + quad * 8;

    f32x4 acc[4];
#pragma unroll
    for (int c = 0; c < 4; ++c) acc[c] = (f32x4){0.f, 0.f, 0.f, 0.f};

#pragma unroll
    for (int ks = 0; ks < 8; ++ks) {
        bf16x8 a = *(const bf16x8*)(aptr + ks * 32);
#pragma unroll
        for (int c = 0; c < 4; ++c) {
            bf16x8 b = *(const bf16x8*)(bptr + (size_t)c * 16 * 256 + ks * 32);
            acc[c] = __builtin_amdgcn_mfma_f32_16x16x32_bf16(a, b, acc[c], 0, 0, 0);
        }
    }

    // epilogue: rows m = m0 + quad*4 + reg ; cols d = c*16 + l15
    float sn[4];
    int nodes[4];
#pragma unroll
    for (int r = 0; r < 4; ++r) {
        nodes[r] = m0 + quad * 4 + r;
        sn[r] = (nodes[r] < N) ? snorm[nodes[r]] : 0.f;
    }
    float s1[4], s2[4];
#pragma unroll
    for (int c = 0; c < 4; ++c) { s1[c] = 0.f; s2[c] = 0.f; }

#pragma unroll
    for (int c = 0; c < 4; ++c) {
        int d = c * 16 + l15;
        float bias = b2[d];
#pragma unroll
        for (int r = 0; r < 4; ++r) {
            float val = (acc[c][r] + bias) * sn[r];
            if (nodes[r] < N) {
                h2[(size_t)nodes[r] * 64 + d] = val;
                s1[c] += val;
                s2[c] = fmaf(val, val, s2[c]);
            }
        }
    }
    // reduce across quads (lanes sharing l15): xor 16, 32
#pragma unroll
    for (int c = 0; c < 4; ++c) {
        s1[c] += __shfl_xor(s1[c], 16);
        s1[c] += __shfl_xor(s1[c], 32);
        s2[c] += __shfl_xor(s2[c], 16);
        s2[c] += __shfl_xor(s2[c], 32);
    }
    if (lane < 16) {
#pragma unroll
        for (int c = 0; c < 4; ++c) {
            int d = c * 16 + l15;
            atomicAdd(&bn_buf[d], s1[c]);
            atomicAdd(&bn_buf[64 + d], s2[c]);
        }
    }
}

// ---------------- K7: BN normalize + relu + residual ----------------
__global__ __launch_bounds__(256) void bn_final_kernel(
    const float* __restrict__ h, const float* __restrict__ h2,
    const float* __restrict__ bn_buf, const float* __restrict__ gamma,
    const float* __restrict__ beta, float* __restrict__ out, int N, float invN)
{
    int idx = blockIdx.x * 256 + threadIdx.x;  // one float4 per thread
    int total4 = N * 16;
    if (idx >= total4) return;
    int base = idx * 4;
    int d0 = base & 63;
    const float4 a = *(const float4*)(h2 + base);
    const float4 hh = *(const float4*)(h + base);
    float r[4] = {a.x, a.y, a.z, a.w};
    float hv[4] = {hh.x, hh.y, hh.z, hh.w};
    float o[4];
#pragma unroll
    for (int k = 0; k < 4; ++k) {
        int d = d0 + k;
        float mu = bn_buf[d] * invN;
        float var = bn_buf[64 + d] * invN - mu * mu;
        float rstd = rsqrtf(var + 1e-5f);
        float x = (r[k] - mu) * rstd * gamma[d] + beta[d];
        o[k] = hv[k] + fmaxf(x, 0.f);
    }
    float4 ov = {o[0], o[1], o[2], o[3]};
    *(float4*)(out + base) = ov;
}

// ---------------- launch ----------------
extern "C" void kernel_launch(void* const* d_in, const int* in_sizes, int n_in,
                              void* d_out, int out_size, void* d_ws, size_t ws_size,
                              hipStream_t stream)
{
    const float* h     = (const float*)d_in[0];
    const float* eig   = (const float*)d_in[1];
    const float* snorm = (const float*)d_in[2];
    const int*   src   = (const int*)d_in[3];
    const int*   dst   = (const int*)d_in[4];
    const float* W1    = (const float*)d_in[5];
    const float* b1    = (const float*)d_in[6];
    const float* W2    = (const float*)d_in[7];
    const float* b2    = (const float*)d_in[8];
    const float* gamma = (const float*)d_in[9];
    const float* beta  = (const float*)d_in[10];
    float* out = (float*)d_out;

    const int N = in_sizes[2];
    const int E = in_sizes[1];
    const int Npad = (N + 63) & ~63;

    // ---- workspace layout (256B aligned slices) ----
    char* w = (char*)d_ws;
    size_t off = 0;
    auto alloc = [&](size_t bytes) -> char* {
        char* p = w + off;
        off += (bytes + 255) & ~size_t(255);
        return p;
    };
    // u,v bf16 contiguous (25.6MB); h2 fp32 aliases the same region after agg
    unsigned short* u = (unsigned short*)alloc((size_t)N * 64 * 2);
    unsigned short* v = (unsigned short*)alloc((size_t)N * 64 * 2);
    float* h2 = (float*)u;   // alias: u,v dead after agg_kernel
    unsigned short* hc = (unsigned short*)alloc((size_t)Npad * 256 * 2);
    int2* csr = (int2*)alloc((size_t)E * 8);
    int*  rank = (int*)alloc((size_t)E * 4);
    // contiguous zero region: cursor (deg histogram) + bn_buf
    char* zero_base = w + off;
    int*   cursor = (int*)alloc((size_t)N * 4);   // becomes deg
    float* bn_buf = (float*)alloc(128 * 4);
    size_t zero_bytes = (size_t)((char*)(bn_buf + 128) - zero_base);
    int* offs = (int*)alloc((size_t)N * 4);
    int nb = (N + 255) / 256;
    int* bsum  = (int*)alloc((size_t)nb * 4);
    int* bscan = (int*)alloc((size_t)nb * 4);
    unsigned short* w2b = (unsigned short*)alloc(64 * 256 * 2);
    (void)ws_size; (void)n_in; (void)out_size;

    hipMemsetAsync(zero_base, 0, zero_bytes, stream);

    int egrid = (E + 255) / 256;
    edge_rank_kernel<<<egrid, 256, 0, stream>>>(dst, cursor, rank, E);
    block_reduce_kernel<<<nb, 256, 0, stream>>>(cursor, bsum, N);
    scan_bsums_kernel<<<1, 1024, 0, stream>>>(bsum, bscan, nb);
    block_scan_kernel<<<nb, 256, 0, stream>>>(cursor, bscan, offs, N);
    csr_scatter_kernel<<<egrid, 256, 0, stream>>>(src, dst, eig, rank, offs, csr, E);

    int ntiles = (N + 63) / 64;
    uv_kernel<<<ntiles, 256, 0, stream>>>(h, W1, b1, u, v, N);
    w2b_kernel<<<64, 256, 0, stream>>>(W2, w2b);

    int agrid = ((size_t)N * 64 + 255) / 256;
    agg_kernel<<<agrid, 256, 0, stream>>>(u, v, h, offs, cursor, csr, hc, N);

    post_mfma_kernel<<<Npad / 64, 256, 0, stream>>>(hc, w2b, b2, snorm, h2, bn_buf, N);

    int fgrid = (N * 16 + 255) / 256;
    bn_final_kernel<<<fgrid, 256, 0, stream>>>(h, h2, bn_buf, gamma, beta, out, N, 1.0f / (float)N);
}

// Round 5
// 435.189 us; speedup vs baseline: 1.1307x; 1.1307x over previous
//
#include <hip/hip_runtime.h>
#include <math.h>

typedef __attribute__((ext_vector_type(8))) short bf16x8;
typedef __attribute__((ext_vector_type(4))) float f32x4;

__device__ __forceinline__ float bf2f(unsigned short s) {
    return __uint_as_float(((unsigned)s) << 16);
}
__device__ __forceinline__ unsigned short f2bf(float f) {
    unsigned u = __float_as_uint(f);
    unsigned r = (u + 0x7fffu + ((u >> 16) & 1u)) >> 16;   // RNE
    return (unsigned short)r;
}

// ---------------- K1: per-edge rank + deg histogram (single atomic) ----------------
__global__ __launch_bounds__(256) void edge_rank_kernel(
    const int* __restrict__ dst, int* __restrict__ cursor, int* __restrict__ rank, int E)
{
    int e = blockIdx.x * 256 + threadIdx.x;
    if (e < E) {
        rank[e] = atomicAdd(&cursor[dst[e]], 1);
    }
}

// ---------------- K2a: per-block reduce of deg ----------------
__global__ __launch_bounds__(256) void block_reduce_kernel(
    const int* __restrict__ deg, int* __restrict__ bsum, int N)
{
    __shared__ int sd[256];
    int t = threadIdx.x;
    int i = blockIdx.x * 256 + t;
    sd[t] = (i < N) ? deg[i] : 0;
    __syncthreads();
    for (int s = 128; s > 0; s >>= 1) {
        if (t < s) sd[t] += sd[t + s];
        __syncthreads();
    }
    if (t == 0) bsum[blockIdx.x] = sd[0];
}

// ---------------- K2b: scan block sums (single block) ----------------
__global__ __launch_bounds__(1024) void scan_bsums_kernel(
    const int* __restrict__ bsum, int* __restrict__ bscan, int nb)
{
    __shared__ int sd[1024];
    int t = threadIdx.x;
    int own = (t < nb) ? bsum[t] : 0;
    sd[t] = own;
    __syncthreads();
    for (int off = 1; off < 1024; off <<= 1) {
        int v = (t >= off) ? sd[t - off] : 0;
        __syncthreads();
        sd[t] += v;
        __syncthreads();
    }
    if (t < nb) bscan[t] = sd[t] - own;   // exclusive prefix
}

// ---------------- K2c: per-block exclusive scan -> offsets ----------------
__global__ __launch_bounds__(256) void block_scan_kernel(
    const int* __restrict__ deg, const int* __restrict__ bscan,
    int* __restrict__ offs, int N)
{
    __shared__ int sd[256];
    int t = threadIdx.x;
    int i = blockIdx.x * 256 + t;
    int myv = (i < N) ? deg[i] : 0;
    sd[t] = myv;
    __syncthreads();
    for (int off = 1; off < 256; off <<= 1) {
        int v = (t >= off) ? sd[t - off] : 0;
        __syncthreads();
        sd[t] += v;
        __syncthreads();
    }
    if (i < N) {
        offs[i] = sd[t] - myv + bscan[blockIdx.x];
    }
}

// ---------------- K3: scatter edges into CSR (no atomics, packed 8B) ----------------
__global__ __launch_bounds__(256) void csr_scatter_kernel(
    const int* __restrict__ src, const int* __restrict__ dst, const float* __restrict__ eig,
    const int* __restrict__ rank, const int* __restrict__ offs,
    int2* __restrict__ csr, int E)
{
    int e = blockIdx.x * 256 + threadIdx.x;
    if (e < E) {
        int dn = dst[e];
        int p = offs[dn] + rank[e];
        csr[p] = make_int2(src[e], __float_as_int(eig[e]));
    }
}

// ---------------- K4: u = h @ A^T ; v = h @ B^T + b1 (bf16 outputs) ----------------
__global__ __launch_bounds__(256) void uv_kernel(
    const float* __restrict__ h, const float* __restrict__ W1, const float* __restrict__ b1,
    unsigned short* __restrict__ u, unsigned short* __restrict__ v, int N)
{
    __shared__ float wT[64 * 128];   // wT[j*128 + c]
    __shared__ float hs[64 * 68];    // hs[n*68 + j], padded
    int t = threadIdx.x;
    for (int idx = t; idx < 64 * 128; idx += 256) {
        int j = idx >> 7, c = idx & 127;
        int d = c & 63;
        int col = (c < 64) ? j : (64 + j);
        wT[idx] = W1[d * 128 + col];
    }
    int n0 = blockIdx.x * 64;
    for (int r = 0; r < 16; ++r) {
        int idx = r * 256 + t;
        int nl = idx >> 6, j = idx & 63;
        int n = n0 + nl;
        hs[nl * 68 + j] = (n < N) ? h[(size_t)n * 64 + j] : 0.f;
    }
    __syncthreads();

    int nb = (t & 15) * 4;
    int cb = (t >> 4) * 8;
    float acc[4][8];
#pragma unroll
    for (int i = 0; i < 4; ++i)
#pragma unroll
        for (int k = 0; k < 8; ++k) acc[i][k] = 0.f;

    for (int j = 0; j < 64; ++j) {
        float wv[8];
#pragma unroll
        for (int k = 0; k < 8; ++k) wv[k] = wT[j * 128 + cb + k];
#pragma unroll
        for (int i = 0; i < 4; ++i) {
            float hv = hs[(nb + i) * 68 + j];
#pragma unroll
            for (int k = 0; k < 8; ++k) acc[i][k] = fmaf(hv, wv[k], acc[i][k]);
        }
    }

    bool isV = (cb >= 64);
    int dbase = cb & 63;
#pragma unroll
    for (int i = 0; i < 4; ++i) {
        int n = n0 + nb + i;
        if (n < N) {
            union { unsigned short s[8]; uint4 v4; } pk;
            if (!isV) {
#pragma unroll
                for (int k = 0; k < 8; ++k) pk.s[k] = f2bf(acc[i][k]);
                *(uint4*)(u + (size_t)n * 64 + dbase) = pk.v4;
            } else {
#pragma unroll
                for (int k = 0; k < 8; ++k) pk.s[k] = f2bf(acc[i][k] + b1[dbase + k]);
                *(uint4*)(v + (size_t)n * 64 + dbase) = pk.v4;
            }
        }
    }
}

// ---------------- K4b: W2 -> bf16 (same row-major [64][256] layout) ----------------
__global__ __launch_bounds__(256) void w2b_kernel(
    const float* __restrict__ W2, unsigned short* __restrict__ w2b)
{
    int idx = blockIdx.x * 256 + threadIdx.x;
    if (idx < 64 * 256) w2b[idx] = f2bf(W2[idx]);
}

// ---------------- K5: aggregation, one wave per node -> hc[N][256] bf16 ----------------
__global__ __launch_bounds__(256) void agg_kernel(
    const unsigned short* __restrict__ u, const unsigned short* __restrict__ v,
    const float* __restrict__ h,
    const int* __restrict__ offs, const int* __restrict__ degi,
    const int2* __restrict__ csr,
    unsigned short* __restrict__ hc, int N)
{
    int gw = (blockIdx.x * 256 + threadIdx.x) >> 6;
    int lane = threadIdx.x & 63;
    int n = __builtin_amdgcn_readfirstlane(gw);
    if (n >= N) return;
    int beg = offs[n];
    int dn = degi[n];

    float accs = 0.f, accd = 0.f, accm = -3.402823466e38f;
    float pa = 0.f, ps = 0.f;   // per-lane partials for absum / sege
    for (int i0 = 0; i0 < dn; i0 += 64) {
        int cnt = min(dn - i0, 64);
        int idxv = 0; float wvv = 0.f;
        if (lane < cnt) {
            int2 rec = csr[beg + i0 + lane];
            idxv = rec.x;
            wvv = __int_as_float(rec.y);
        }
        pa += fabsf(wvv);
        ps += wvv;
        int j = 0;
        for (; j + 4 <= cnt; j += 4) {
            int s0 = __shfl(idxv, j), s1 = __shfl(idxv, j + 1);
            int s2 = __shfl(idxv, j + 2), s3 = __shfl(idxv, j + 3);
            float w0 = __shfl(wvv, j), w1 = __shfl(wvv, j + 1);
            float w2_ = __shfl(wvv, j + 2), w3 = __shfl(wvv, j + 3);
            float u0 = bf2f(u[(size_t)s0 * 64 + lane]);
            float u1 = bf2f(u[(size_t)s1 * 64 + lane]);
            float u2 = bf2f(u[(size_t)s2 * 64 + lane]);
            float u3 = bf2f(u[(size_t)s3 * 64 + lane]);
            accs += (u0 + u1) + (u2 + u3);
            accm = fmaxf(accm, fmaxf(fmaxf(u0, u1), fmaxf(u2, u3)));
            accd = fmaf(w0, u0, fmaf(w1, u1, fmaf(w2_, u2, fmaf(w3, u3, accd))));
        }
        for (; j < cnt; ++j) {
            int s0 = __shfl(idxv, j);
            float w0 = __shfl(wvv, j);
            float u0 = bf2f(u[(size_t)s0 * 64 + lane]);
            accs += u0;
            accm = fmaxf(accm, u0);
            accd = fmaf(w0, u0, accd);
        }
    }
#pragma unroll
    for (int w = 1; w < 64; w <<= 1) {
        pa += __shfl_xor(pa, w);
        ps += __shfl_xor(ps, w);
    }
    float inv_ab = 1.f / (pa + 1e-8f);
    float segw = ps * inv_ab;

    float vl = bf2f(v[(size_t)n * 64 + lane]);
    float hl = h[(size_t)n * 64 + lane];
    float fdeg = (float)dn;
    float mean = (accs + fdeg * vl) / fmaxf(fdeg, 1.f);
    float amax = (dn > 0) ? (accm + vl) : 0.f;
    float adir = fabsf(fmaf(accd, inv_ab, segw * (vl - hl)));
    size_t base = (size_t)n * 256;
    hc[base + lane]       = f2bf(hl);
    hc[base + 64 + lane]  = f2bf(mean);
    hc[base + 128 + lane] = f2bf(amax);
    hc[base + 192 + lane] = f2bf(adir);
}

// ---------------- K6: posttrans via MFMA (transposed): h2^T = W2 * hc^T ----------------
// block = 4 waves = 4 d-stripes of 16; all waves sweep the SAME contiguous range of
// 16-node tiles (hc rows shared through L1/L2). A = W2 stripe register-cached once.
// Per tile: 8 B-loads (hc rows, 16B/lane) + 8 MFMA; epilogue = one float4 store/lane.
__global__ __launch_bounds__(256) void post_mfma_kernel(
    const unsigned short* __restrict__ hc, const unsigned short* __restrict__ w2b,
    const float* __restrict__ b2, const float* __restrict__ snorm,
    float* __restrict__ h2, float* __restrict__ bn_buf, int ntiles, int tpb, int N)
{
    int tid = threadIdx.x;
    int lane = tid & 63;
    int l15 = lane & 15;
    int quad = lane >> 4;
    int wv = tid >> 6;
    int d0 = wv * 16;

    // A fragments: W2 rows d0+l15, cached for the whole kernel (8 frags = 32 VGPR)
    const unsigned short* abase = w2b + (size_t)(d0 + l15) * 256 + quad * 8;
    bf16x8 afrag[8];
#pragma unroll
    for (int ks = 0; ks < 8; ++ks) afrag[ks] = *(const bf16x8*)(abase + ks * 32);

    float4 b2v = *(const float4*)(b2 + d0 + quad * 4);

    int t0 = blockIdx.x * tpb;
    int t1 = min(t0 + tpb, ntiles);

    float s1[4] = {0.f, 0.f, 0.f, 0.f};
    float s2[4] = {0.f, 0.f, 0.f, 0.f};

    for (int t = t0; t < t1; ++t) {
        int node = t * 16 + l15;
        const unsigned short* bbase = hc + (size_t)node * 256 + quad * 8;
        bf16x8 bfrag[8];
#pragma unroll
        for (int ks = 0; ks < 8; ++ks) bfrag[ks] = *(const bf16x8*)(bbase + ks * 32);

        f32x4 acc = (f32x4){0.f, 0.f, 0.f, 0.f};
#pragma unroll
        for (int ks = 0; ks < 8; ++ks)
            acc = __builtin_amdgcn_mfma_f32_16x16x32_bf16(afrag[ks], bfrag[ks], acc, 0, 0, 0);

        float sn = (node < N) ? snorm[node] : 0.f;
        float4 val;
        val.x = (acc[0] + b2v.x) * sn;
        val.y = (acc[1] + b2v.y) * sn;
        val.z = (acc[2] + b2v.z) * sn;
        val.w = (acc[3] + b2v.w) * sn;
        s1[0] += val.x; s2[0] = fmaf(val.x, val.x, s2[0]);
        s1[1] += val.y; s2[1] = fmaf(val.y, val.y, s2[1]);
        s1[2] += val.z; s2[2] = fmaf(val.z, val.z, s2[2]);
        s1[3] += val.w; s2[3] = fmaf(val.w, val.w, s2[3]);
        if (node < N)
            *(float4*)(h2 + (size_t)node * 64 + d0 + quad * 4) = val;
    }

    // reduce over l15 (lanes sharing the same d), then 8 atomics per wave
#pragma unroll
    for (int r = 0; r < 4; ++r) {
#pragma unroll
        for (int m = 1; m < 16; m <<= 1) {
            s1[r] += __shfl_xor(s1[r], m);
            s2[r] += __shfl_xor(s2[r], m);
        }
    }
    if (l15 == 0) {
#pragma unroll
        for (int r = 0; r < 4; ++r) {
            int d = d0 + quad * 4 + r;
            atomicAdd(&bn_buf[d], s1[r]);
            atomicAdd(&bn_buf[64 + d], s2[r]);
        }
    }
}

// ---------------- K7: BN normalize + relu + residual ----------------
__global__ __launch_bounds__(256) void bn_final_kernel(
    const float* __restrict__ h, const float* __restrict__ h2,
    const float* __restrict__ bn_buf, const float* __restrict__ gamma,
    const float* __restrict__ beta, float* __restrict__ out, int N, float invN)
{
    int idx = blockIdx.x * 256 + threadIdx.x;  // one float4 per thread
    int total4 = N * 16;
    if (idx >= total4) return;
    int base = idx * 4;
    int d0 = base & 63;
    const float4 a = *(const float4*)(h2 + base);
    const float4 hh = *(const float4*)(h + base);
    float r[4] = {a.x, a.y, a.z, a.w};
    float hv[4] = {hh.x, hh.y, hh.z, hh.w};
    float o[4];
#pragma unroll
    for (int k = 0; k < 4; ++k) {
        int d = d0 + k;
        float mu = bn_buf[d] * invN;
        float var = bn_buf[64 + d] * invN - mu * mu;
        float rstd = rsqrtf(var + 1e-5f);
        float x = (r[k] - mu) * rstd * gamma[d] + beta[d];
        o[k] = hv[k] + fmaxf(x, 0.f);
    }
    float4 ov = {o[0], o[1], o[2], o[3]};
    *(float4*)(out + base) = ov;
}

// ---------------- launch ----------------
extern "C" void kernel_launch(void* const* d_in, const int* in_sizes, int n_in,
                              void* d_out, int out_size, void* d_ws, size_t ws_size,
                              hipStream_t stream)
{
    const float* h     = (const float*)d_in[0];
    const float* eig   = (const float*)d_in[1];
    const float* snorm = (const float*)d_in[2];
    const int*   src   = (const int*)d_in[3];
    const int*   dst   = (const int*)d_in[4];
    const float* W1    = (const float*)d_in[5];
    const float* b1    = (const float*)d_in[6];
    const float* W2    = (const float*)d_in[7];
    const float* b2    = (const float*)d_in[8];
    const float* gamma = (const float*)d_in[9];
    const float* beta  = (const float*)d_in[10];
    float* out = (float*)d_out;

    const int N = in_sizes[2];
    const int E = in_sizes[1];
    const int Npad = (N + 63) & ~63;

    // ---- workspace layout (256B aligned slices) ----
    char* w = (char*)d_ws;
    size_t off = 0;
    auto alloc = [&](size_t bytes) -> char* {
        char* p = w + off;
        off += (bytes + 255) & ~size_t(255);
        return p;
    };
    // u,v bf16 contiguous (25.6MB); h2 fp32 aliases the same region after agg
    unsigned short* u = (unsigned short*)alloc((size_t)N * 64 * 2);
    unsigned short* v = (unsigned short*)alloc((size_t)N * 64 * 2);
    float* h2 = (float*)u;   // alias: u,v dead after agg_kernel
    unsigned short* hc = (unsigned short*)alloc((size_t)Npad * 256 * 2);
    int2* csr = (int2*)alloc((size_t)E * 8);
    int*  rank = (int*)alloc((size_t)E * 4);
    // contiguous zero region: cursor (deg histogram) + bn_buf
    char* zero_base = w + off;
    int*   cursor = (int*)alloc((size_t)N * 4);   // becomes deg
    float* bn_buf = (float*)alloc(128 * 4);
    size_t zero_bytes = (size_t)((char*)(bn_buf + 128) - zero_base);
    int* offs = (int*)alloc((size_t)N * 4);
    int nb = (N + 255) / 256;
    int* bsum  = (int*)alloc((size_t)nb * 4);
    int* bscan = (int*)alloc((size_t)nb * 4);
    unsigned short* w2b = (unsigned short*)alloc(64 * 256 * 2);
    (void)ws_size; (void)n_in; (void)out_size;

    hipMemsetAsync(zero_base, 0, zero_bytes, stream);
    if (Npad > N)   // zero hc tail rows so padded MFMA tiles are benign
        hipMemsetAsync(hc + (size_t)N * 256, 0, (size_t)(Npad - N) * 256 * 2, stream);

    int egrid = (E + 255) / 256;
    edge_rank_kernel<<<egrid, 256, 0, stream>>>(dst, cursor, rank, E);
    block_reduce_kernel<<<nb, 256, 0, stream>>>(cursor, bsum, N);
    scan_bsums_kernel<<<1, 1024, 0, stream>>>(bsum, bscan, nb);
    block_scan_kernel<<<nb, 256, 0, stream>>>(cursor, bscan, offs, N);
    csr_scatter_kernel<<<egrid, 256, 0, stream>>>(src, dst, eig, rank, offs, csr, E);

    int ntiles_uv = (N + 63) / 64;
    uv_kernel<<<ntiles_uv, 256, 0, stream>>>(h, W1, b1, u, v, N);
    w2b_kernel<<<64, 256, 0, stream>>>(W2, w2b);

    int agrid = ((size_t)N * 64 + 255) / 256;
    agg_kernel<<<agrid, 256, 0, stream>>>(u, v, h, offs, cursor, csr, hc, N);

    int ptiles = Npad / 16;
    int pblocks = 1024;
    int tpb = (ptiles + pblocks - 1) / pblocks;
    post_mfma_kernel<<<pblocks, 256, 0, stream>>>(hc, w2b, b2, snorm, h2, bn_buf,
                                                  ptiles, tpb, N);

    int fgrid = (N * 16 + 255) / 256;
    bn_final_kernel<<<fgrid, 256, 0, stream>>>(h, h2, bn_buf, gamma, beta, out, N, 1.0f / (float)N);
}

// Round 6
// 415.918 us; speedup vs baseline: 1.1831x; 1.0463x over previous
//
#include <hip/hip_runtime.h>
#include <math.h>

typedef __attribute__((ext_vector_type(8))) short bf16x8;
typedef __attribute__((ext_vector_type(4))) float f32x4;

__device__ __forceinline__ float bf2f(unsigned short s) {
    return __uint_as_float(((unsigned)s) << 16);
}
__device__ __forceinline__ unsigned short f2bf(float f) {
    unsigned u = __float_as_uint(f);
    unsigned r = (u + 0x7fffu + ((u >> 16) & 1u)) >> 16;   // RNE
    return (unsigned short)r;
}

// ---------------- K1: per-edge rank + deg histogram (single atomic) ----------------
__global__ __launch_bounds__(256) void edge_rank_kernel(
    const int* __restrict__ dst, int* __restrict__ cursor, int* __restrict__ rank, int E)
{
    int e = blockIdx.x * 256 + threadIdx.x;
    if (e < E) {
        rank[e] = atomicAdd(&cursor[dst[e]], 1);
    }
}

// ---------------- K2a: per-block reduce of deg ----------------
__global__ __launch_bounds__(256) void block_reduce_kernel(
    const int* __restrict__ deg, int* __restrict__ bsum, int N)
{
    __shared__ int sd[256];
    int t = threadIdx.x;
    int i = blockIdx.x * 256 + t;
    sd[t] = (i < N) ? deg[i] : 0;
    __syncthreads();
    for (int s = 128; s > 0; s >>= 1) {
        if (t < s) sd[t] += sd[t + s];
        __syncthreads();
    }
    if (t == 0) bsum[blockIdx.x] = sd[0];
}

// ---------------- K2b: scan block sums (single block) ----------------
__global__ __launch_bounds__(1024) void scan_bsums_kernel(
    const int* __restrict__ bsum, int* __restrict__ bscan, int nb)
{
    __shared__ int sd[1024];
    int t = threadIdx.x;
    int own = (t < nb) ? bsum[t] : 0;
    sd[t] = own;
    __syncthreads();
    for (int off = 1; off < 1024; off <<= 1) {
        int v = (t >= off) ? sd[t - off] : 0;
        __syncthreads();
        sd[t] += v;
        __syncthreads();
    }
    if (t < nb) bscan[t] = sd[t] - own;   // exclusive prefix
}

// ---------------- K2c: per-block exclusive scan -> offsets ----------------
__global__ __launch_bounds__(256) void block_scan_kernel(
    const int* __restrict__ deg, const int* __restrict__ bscan,
    int* __restrict__ offs, int N)
{
    __shared__ int sd[256];
    int t = threadIdx.x;
    int i = blockIdx.x * 256 + t;
    int myv = (i < N) ? deg[i] : 0;
    sd[t] = myv;
    __syncthreads();
    for (int off = 1; off < 256; off <<= 1) {
        int v = (t >= off) ? sd[t - off] : 0;
        __syncthreads();
        sd[t] += v;
        __syncthreads();
    }
    if (i < N) {
        offs[i] = sd[t] - myv + bscan[blockIdx.x];
    }
}

// ---------------- K3: scatter edges into CSR (no atomics, packed 8B) ----------------
__global__ __launch_bounds__(256) void csr_scatter_kernel(
    const int* __restrict__ src, const int* __restrict__ dst, const float* __restrict__ eig,
    const int* __restrict__ rank, const int* __restrict__ offs,
    int2* __restrict__ csr, int E)
{
    int e = blockIdx.x * 256 + threadIdx.x;
    if (e < E) {
        int dn = dst[e];
        int p = offs[dn] + rank[e];
        csr[p] = make_int2(src[e], __float_as_int(eig[e]));
    }
}

// ---------------- K4: u = h @ A^T ; v = h @ B^T + b1 (bf16 outputs) ----------------
__global__ __launch_bounds__(256) void uv_kernel(
    const float* __restrict__ h, const float* __restrict__ W1, const float* __restrict__ b1,
    unsigned short* __restrict__ u, unsigned short* __restrict__ v, int N)
{
    __shared__ float wT[64 * 128];   // wT[j*128 + c]
    __shared__ float hs[64 * 68];    // hs[n*68 + j], padded
    int t = threadIdx.x;
    for (int idx = t; idx < 64 * 128; idx += 256) {
        int j = idx >> 7, c = idx & 127;
        int d = c & 63;
        int col = (c < 64) ? j : (64 + j);
        wT[idx] = W1[d * 128 + col];
    }
    int n0 = blockIdx.x * 64;
    for (int r = 0; r < 16; ++r) {
        int idx = r * 256 + t;
        int nl = idx >> 6, j = idx & 63;
        int n = n0 + nl;
        hs[nl * 68 + j] = (n < N) ? h[(size_t)n * 64 + j] : 0.f;
    }
    __syncthreads();

    int nb = (t & 15) * 4;
    int cb = (t >> 4) * 8;
    float acc[4][8];
#pragma unroll
    for (int i = 0; i < 4; ++i)
#pragma unroll
        for (int k = 0; k < 8; ++k) acc[i][k] = 0.f;

    for (int j = 0; j < 64; ++j) {
        float wv[8];
#pragma unroll
        for (int k = 0; k < 8; ++k) wv[k] = wT[j * 128 + cb + k];
#pragma unroll
        for (int i = 0; i < 4; ++i) {
            float hv = hs[(nb + i) * 68 + j];
#pragma unroll
            for (int k = 0; k < 8; ++k) acc[i][k] = fmaf(hv, wv[k], acc[i][k]);
        }
    }

    bool isV = (cb >= 64);
    int dbase = cb & 63;
#pragma unroll
    for (int i = 0; i < 4; ++i) {
        int n = n0 + nb + i;
        if (n < N) {
            union { unsigned short s[8]; uint4 v4; } pk;
            if (!isV) {
#pragma unroll
                for (int k = 0; k < 8; ++k) pk.s[k] = f2bf(acc[i][k]);
                *(uint4*)(u + (size_t)n * 64 + dbase) = pk.v4;
            } else {
#pragma unroll
                for (int k = 0; k < 8; ++k) pk.s[k] = f2bf(acc[i][k] + b1[dbase + k]);
                *(uint4*)(v + (size_t)n * 64 + dbase) = pk.v4;
            }
        }
    }
}

// ---------------- K4b: W2 -> bf16 (same row-major [64][256] layout) ----------------
__global__ __launch_bounds__(256) void w2b_kernel(
    const float* __restrict__ W2, unsigned short* __restrict__ w2b)
{
    int idx = blockIdx.x * 256 + threadIdx.x;
    if (idx < 64 * 256) w2b[idx] = f2bf(W2[idx]);
}

// ---------------- K5: aggregation, one wave per node -> hc[N][256] bf16 ----------------
__global__ __launch_bounds__(256) void agg_kernel(
    const unsigned short* __restrict__ u, const unsigned short* __restrict__ v,
    const float* __restrict__ h,
    const int* __restrict__ offs, const int* __restrict__ degi,
    const int2* __restrict__ csr,
    unsigned short* __restrict__ hc, int N)
{
    int gw = (blockIdx.x * 256 + threadIdx.x) >> 6;
    int lane = threadIdx.x & 63;
    int n = __builtin_amdgcn_readfirstlane(gw);
    if (n >= N) return;
    int beg = offs[n];
    int dn = degi[n];

    float accs = 0.f, accd = 0.f, accm = -3.402823466e38f;
    float pa = 0.f, ps = 0.f;   // per-lane partials for absum / sege
    for (int i0 = 0; i0 < dn; i0 += 64) {
        int cnt = min(dn - i0, 64);
        int idxv = 0; float wvv = 0.f;
        if (lane < cnt) {
            int2 rec = csr[beg + i0 + lane];
            idxv = rec.x;
            wvv = __int_as_float(rec.y);
        }
        pa += fabsf(wvv);
        ps += wvv;
        int j = 0;
        for (; j + 4 <= cnt; j += 4) {
            int s0 = __shfl(idxv, j), s1 = __shfl(idxv, j + 1);
            int s2 = __shfl(idxv, j + 2), s3 = __shfl(idxv, j + 3);
            float w0 = __shfl(wvv, j), w1 = __shfl(wvv, j + 1);
            float w2_ = __shfl(wvv, j + 2), w3 = __shfl(wvv, j + 3);
            float u0 = bf2f(u[(size_t)s0 * 64 + lane]);
            float u1 = bf2f(u[(size_t)s1 * 64 + lane]);
            float u2 = bf2f(u[(size_t)s2 * 64 + lane]);
            float u3 = bf2f(u[(size_t)s3 * 64 + lane]);
            accs += (u0 + u1) + (u2 + u3);
            accm = fmaxf(accm, fmaxf(fmaxf(u0, u1), fmaxf(u2, u3)));
            accd = fmaf(w0, u0, fmaf(w1, u1, fmaf(w2_, u2, fmaf(w3, u3, accd))));
        }
        for (; j < cnt; ++j) {
            int s0 = __shfl(idxv, j);
            float w0 = __shfl(wvv, j);
            float u0 = bf2f(u[(size_t)s0 * 64 + lane]);
            accs += u0;
            accm = fmaxf(accm, u0);
            accd = fmaf(w0, u0, accd);
        }
    }
#pragma unroll
    for (int w = 1; w < 64; w <<= 1) {
        pa += __shfl_xor(pa, w);
        ps += __shfl_xor(ps, w);
    }
    float inv_ab = 1.f / (pa + 1e-8f);
    float segw = ps * inv_ab;

    float vl = bf2f(v[(size_t)n * 64 + lane]);
    float hl = h[(size_t)n * 64 + lane];
    float fdeg = (float)dn;
    float mean = (accs + fdeg * vl) / fmaxf(fdeg, 1.f);
    float amax = (dn > 0) ? (accm + vl) : 0.f;
    float adir = fabsf(fmaf(accd, inv_ab, segw * (vl - hl)));
    size_t base = (size_t)n * 256;
    hc[base + lane]       = f2bf(hl);
    hc[base + 64 + lane]  = f2bf(mean);
    hc[base + 128 + lane] = f2bf(amax);
    hc[base + 192 + lane] = f2bf(adir);
}

// ---------------- K6: posttrans via MFMA (transposed): h2^T = W2 * hc^T ----------------
// block = 4 waves = 4 d-stripes of 16; all waves sweep the SAME contiguous range of
// 16-node tiles. A = W2 stripe register-cached (32 VGPR). B double-buffered:
// load tile t+1's 8 frags while MFMA-ing tile t. __launch_bounds__(256,2) keeps
// the register allocator from rematerializing the fragment loads (R5: VGPR=36 bug).
__global__ __launch_bounds__(256, 2) void post_mfma_kernel(
    const unsigned short* __restrict__ hc, const unsigned short* __restrict__ w2b,
    const float* __restrict__ b2, const float* __restrict__ snorm,
    float* __restrict__ h2, float* __restrict__ bn_buf, int ntiles, int tpb, int N)
{
    int tid = threadIdx.x;
    int lane = tid & 63;
    int l15 = lane & 15;
    int quad = lane >> 4;
    int wv = tid >> 6;
    int d0 = wv * 16;

    // A fragments: W2 rows d0+l15, cached for the whole kernel (8 frags = 32 VGPR)
    const unsigned short* abase = w2b + (size_t)(d0 + l15) * 256 + quad * 8;
    bf16x8 afrag[8];
#pragma unroll
    for (int ks = 0; ks < 8; ++ks) afrag[ks] = *(const bf16x8*)(abase + ks * 32);

    float4 b2v = *(const float4*)(b2 + d0 + quad * 4);

    int t0 = blockIdx.x * tpb;
    int t1 = min(t0 + tpb, ntiles);
    if (t0 >= t1) return;

    float s1[4] = {0.f, 0.f, 0.f, 0.f};
    float s2[4] = {0.f, 0.f, 0.f, 0.f};

    bf16x8 bufA[8], bufB[8];
    float snA, snB;

    // prologue: load tile t0 into bufA
    {
        int node = t0 * 16 + l15;
        const unsigned short* bb = hc + (size_t)node * 256 + quad * 8;
#pragma unroll
        for (int ks = 0; ks < 8; ++ks) bufA[ks] = *(const bf16x8*)(bb + ks * 32);
        snA = (node < N) ? snorm[node] : 0.f;
    }

#pragma unroll 2
    for (int t = t0; t < t1; ++t) {
        bool even = ((t - t0) & 1) == 0;
        bf16x8* cur = even ? bufA : bufB;
        bf16x8* nxt = even ? bufB : bufA;
        float sn = even ? snA : snB;
        if (t + 1 < t1) {
            int nn = (t + 1) * 16 + l15;
            const unsigned short* bb = hc + (size_t)nn * 256 + quad * 8;
#pragma unroll
            for (int ks = 0; ks < 8; ++ks) nxt[ks] = *(const bf16x8*)(bb + ks * 32);
            float s = (nn < N) ? snorm[nn] : 0.f;
            if (even) snB = s; else snA = s;
        }

        f32x4 acc = (f32x4){0.f, 0.f, 0.f, 0.f};
#pragma unroll
        for (int ks = 0; ks < 8; ++ks)
            acc = __builtin_amdgcn_mfma_f32_16x16x32_bf16(afrag[ks], cur[ks], acc, 0, 0, 0);

        int node = t * 16 + l15;
        float4 val;
        val.x = (acc[0] + b2v.x) * sn;
        val.y = (acc[1] + b2v.y) * sn;
        val.z = (acc[2] + b2v.z) * sn;
        val.w = (acc[3] + b2v.w) * sn;
        s1[0] += val.x; s2[0] = fmaf(val.x, val.x, s2[0]);
        s1[1] += val.y; s2[1] = fmaf(val.y, val.y, s2[1]);
        s1[2] += val.z; s2[2] = fmaf(val.z, val.z, s2[2]);
        s1[3] += val.w; s2[3] = fmaf(val.w, val.w, s2[3]);
        if (node < N)
            *(float4*)(h2 + (size_t)node * 64 + d0 + quad * 4) = val;
    }

    // reduce over l15 (lanes sharing the same d), then 8 atomics per wave
#pragma unroll
    for (int r = 0; r < 4; ++r) {
#pragma unroll
        for (int m = 1; m < 16; m <<= 1) {
            s1[r] += __shfl_xor(s1[r], m);
            s2[r] += __shfl_xor(s2[r], m);
        }
    }
    if (l15 == 0) {
#pragma unroll
        for (int r = 0; r < 4; ++r) {
            int d = d0 + quad * 4 + r;
            atomicAdd(&bn_buf[d], s1[r]);
            atomicAdd(&bn_buf[64 + d], s2[r]);
        }
    }
}

// ---------------- K7: BN normalize + relu + residual ----------------
__global__ __launch_bounds__(256) void bn_final_kernel(
    const float* __restrict__ h, const float* __restrict__ h2,
    const float* __restrict__ bn_buf, const float* __restrict__ gamma,
    const float* __restrict__ beta, float* __restrict__ out, int N, float invN)
{
    int idx = blockIdx.x * 256 + threadIdx.x;  // one float4 per thread
    int total4 = N * 16;
    if (idx >= total4) return;
    int base = idx * 4;
    int d0 = base & 63;
    const float4 a = *(const float4*)(h2 + base);
    const float4 hh = *(const float4*)(h + base);
    float r[4] = {a.x, a.y, a.z, a.w};
    float hv[4] = {hh.x, hh.y, hh.z, hh.w};
    float o[4];
#pragma unroll
    for (int k = 0; k < 4; ++k) {
        int d = d0 + k;
        float mu = bn_buf[d] * invN;
        float var = bn_buf[64 + d] * invN - mu * mu;
        float rstd = rsqrtf(var + 1e-5f);
        float x = (r[k] - mu) * rstd * gamma[d] + beta[d];
        o[k] = hv[k] + fmaxf(x, 0.f);
    }
    float4 ov = {o[0], o[1], o[2], o[3]};
    *(float4*)(out + base) = ov;
}

// ---------------- launch ----------------
extern "C" void kernel_launch(void* const* d_in, const int* in_sizes, int n_in,
                              void* d_out, int out_size, void* d_ws, size_t ws_size,
                              hipStream_t stream)
{
    const float* h     = (const float*)d_in[0];
    const float* eig   = (const float*)d_in[1];
    const float* snorm = (const float*)d_in[2];
    const int*   src   = (const int*)d_in[3];
    const int*   dst   = (const int*)d_in[4];
    const float* W1    = (const float*)d_in[5];
    const float* b1    = (const float*)d_in[6];
    const float* W2    = (const float*)d_in[7];
    const float* b2    = (const float*)d_in[8];
    const float* gamma = (const float*)d_in[9];
    const float* beta  = (const float*)d_in[10];
    float* out = (float*)d_out;

    const int N = in_sizes[2];
    const int E = in_sizes[1];
    const int Npad = (N + 63) & ~63;

    // ---- workspace layout (256B aligned slices) ----
    char* w = (char*)d_ws;
    size_t off = 0;
    auto alloc = [&](size_t bytes) -> char* {
        char* p = w + off;
        off += (bytes + 255) & ~size_t(255);
        return p;
    };
    // u,v bf16 contiguous (25.6MB); h2 fp32 aliases the same region after agg
    unsigned short* u = (unsigned short*)alloc((size_t)N * 64 * 2);
    unsigned short* v = (unsigned short*)alloc((size_t)N * 64 * 2);
    float* h2 = (float*)u;   // alias: u,v dead after agg_kernel
    unsigned short* hc = (unsigned short*)alloc((size_t)Npad * 256 * 2);
    int2* csr = (int2*)alloc((size_t)E * 8);
    int*  rank = (int*)alloc((size_t)E * 4);
    // contiguous zero region: cursor (deg histogram) + bn_buf
    char* zero_base = w + off;
    int*   cursor = (int*)alloc((size_t)N * 4);   // becomes deg
    float* bn_buf = (float*)alloc(128 * 4);
    size_t zero_bytes = (size_t)((char*)(bn_buf + 128) - zero_base);
    int* offs = (int*)alloc((size_t)N * 4);
    int nb = (N + 255) / 256;
    int* bsum  = (int*)alloc((size_t)nb * 4);
    int* bscan = (int*)alloc((size_t)nb * 4);
    unsigned short* w2b = (unsigned short*)alloc(64 * 256 * 2);
    (void)ws_size; (void)n_in; (void)out_size;

    hipMemsetAsync(zero_base, 0, zero_bytes, stream);
    if (Npad > N)   // zero hc tail rows so padded MFMA tiles are benign
        hipMemsetAsync(hc + (size_t)N * 256, 0, (size_t)(Npad - N) * 256 * 2, stream);

    int egrid = (E + 255) / 256;
    edge_rank_kernel<<<egrid, 256, 0, stream>>>(dst, cursor, rank, E);
    block_reduce_kernel<<<nb, 256, 0, stream>>>(cursor, bsum, N);
    scan_bsums_kernel<<<1, 1024, 0, stream>>>(bsum, bscan, nb);
    block_scan_kernel<<<nb, 256, 0, stream>>>(cursor, bscan, offs, N);
    csr_scatter_kernel<<<egrid, 256, 0, stream>>>(src, dst, eig, rank, offs, csr, E);

    int ntiles_uv = (N + 63) / 64;
    uv_kernel<<<ntiles_uv, 256, 0, stream>>>(h, W1, b1, u, v, N);
    w2b_kernel<<<64, 256, 0, stream>>>(W2, w2b);

    int agrid = ((size_t)N * 64 + 255) / 256;
    agg_kernel<<<agrid, 256, 0, stream>>>(u, v, h, offs, cursor, csr, hc, N);

    int ptiles = Npad / 16;
    int pblocks = 1024;
    int tpb = (ptiles + pblocks - 1) / pblocks;
    post_mfma_kernel<<<pblocks, 256, 0, stream>>>(hc, w2b, b2, snorm, h2, bn_buf,
                                                  ptiles, tpb, N);

    int fgrid = (N * 16 + 255) / 256;
    bn_final_kernel<<<fgrid, 256, 0, stream>>>(h, h2, bn_buf, gamma, beta, out, N, 1.0f / (float)N);
}